// Round 3
// baseline (209.296 us; speedup 1.0000x reference)
//
#include <hip/hip_runtime.h>
#include <hip/hip_bf16.h>
#include <math.h>

#define B_ 64
#define N_ 64
#define C_ 8
#define F_ 256
#define K_ 2048    // C_*F_
#define NO_ 2048   // OC_*OF_
#define M_TOT 4160 // 64 (zx rows) + 4096 (zn rows)

typedef __attribute__((ext_vector_type(8))) short bf16x8;  // 8 bf16 = 4 VGPRs
typedef __attribute__((ext_vector_type(4))) float f32x4;

__device__ __forceinline__ unsigned short bfbits(float f) {
    union { __hip_bfloat16 h; unsigned short u; } cv;
    cv.h = __float2bfloat16(f);
    return cv.u;
}

// ---------------------------------------------------------------------------
// Fused: s1[b], s2[b,n] reductions + Wc fp32->bf16 conversion.
// blk < 4096: s2;  4096..4159: s1;  >=4160: wc convert.
__global__ __launch_bounds__(256) void sums_wc_k(const float* __restrict__ x,
        const float* __restrict__ nb, const float* __restrict__ W1,
        const float* __restrict__ W2, const float* __restrict__ Wc,
        float* __restrict__ s1, float* __restrict__ s2,
        __hip_bfloat16* __restrict__ Bbuf) {
    int blk = blockIdx.x;
    int f = threadIdx.x;
    if (blk >= B_ * N_ + B_) {
        int i = (blk - (B_ * N_ + B_)) * 1024 + f * 4;
        float4 v = *(const float4*)(Wc + i);
        ushort4 u = { bfbits(v.x), bfbits(v.y), bfbits(v.z), bfbits(v.w) };
        *(ushort4*)(&Bbuf[i]) = u;            // one 8B store (was 4x 2B)
        return;
    }
    float val;
    if (blk < B_ * N_) {
        const float* base = nb + (size_t)blk * (C_ * F_);
        float wsum = 0.f;
        #pragma unroll
        for (int k = 0; k < C_; ++k) wsum += W2[k * F_ + f];
        float cs = 0.f;
        #pragma unroll
        for (int c = 0; c < C_; ++c) cs += base[c * F_ + f];
        val = cs * wsum;
    } else {
        int b = blk - B_ * N_;
        const float* base = x + (size_t)b * (C_ * F_);
        float wsum = 0.f;
        #pragma unroll
        for (int k = 0; k < C_; ++k) wsum += W1[k * F_ + f];
        float cs = 0.f;
        #pragma unroll
        for (int c = 0; c < C_; ++c) cs += base[c * F_ + f];
        val = cs * wsum;
    }
    #pragma unroll
    for (int off = 32; off > 0; off >>= 1) val += __shfl_down(val, off, 64);
    __shared__ float wred[4];
    int w = f >> 6;
    if ((f & 63) == 0) wred[w] = val;
    __syncthreads();
    if (f == 0) {
        float s = wred[0] + wred[1] + wred[2] + wred[3];
        if (blk < B_ * N_) s2[blk] = s;
        else s1[blk - B_ * N_] = s;
    }
}

// ---------------------------------------------------------------------------
// t[b,c,d] = s1[b] * sum_n nb[b,n,c,d] * s2[b,n]
__global__ __launch_bounds__(1024) void t_k(const float* __restrict__ nb,
        const float* __restrict__ s1, const float* __restrict__ s2,
        float* __restrict__ t) {
    int blk = blockIdx.x;  // b*C_ + c
    int b = blk / C_, c = blk % C_;
    int tid = threadIdx.x;
    int q = tid >> 8, d = tid & 255;
    const float* p = nb + ((size_t)(b * N_) * C_ + c) * F_ + d;
    const float* s2p = s2 + b * N_;
    float acc = 0.f;
    #pragma unroll
    for (int j = 0; j < 16; ++j) {
        int n = q * 16 + j;
        acc += p[(size_t)n * C_ * F_] * s2p[n];
    }
    __shared__ float part[4][F_];
    part[q][d] = acc;
    __syncthreads();
    if (tid < 256) {
        float s = part[0][d] + part[1][d] + part[2][d] + part[3][d];
        t[(size_t)blk * F_ + d] = s * s1[b];
    }
}

// ---------------------------------------------------------------------------
// rdenom[b,a,d] = 1 / (1e-7 + sum_c |sgnroot(x_a t_d + x_d t_a)|)
__global__ __launch_bounds__(256) void denom_k(const float* __restrict__ x,
        const float* __restrict__ t, float* __restrict__ rdenom) {
    int blk = blockIdx.x;  // b*F_ + a
    int b = blk >> 8, a = blk & 255;
    int d = threadIdx.x;
    float acc = 1e-7f;
    #pragma unroll
    for (int c = 0; c < C_; ++c) {
        size_t o = ((size_t)b * C_ + c) * F_;
        float xa = x[o + a], ta = t[o + a];
        float xd = x[o + d], td = t[o + d];
        float v = xa * td + xd * ta;
        float r = __builtin_amdgcn_sqrtf(fmaxf(fabsf(v), 1e-8f));
        acc += (v != 0.f) ? r : 0.f;
    }
    rdenom[(size_t)blk * F_ + d] = __builtin_amdgcn_rcpf(acc);
}

__device__ __forceinline__ float sgnroot_dev(float v) {
    float r = __builtin_amdgcn_sqrtf(fmaxf(fabsf(v), 1e-8f));
    return (v > 0.f) ? r : ((v < 0.f) ? -r : 0.f);
}

// ---------------------------------------------------------------------------
// Fused zx+zn via MFMA. One block per (b,c).
// R3: (a) packed 8B LDS staging writes (was 64 scalar ds_write_b16/thread);
//     (b) accumulators for all 4 atiles held in registers (acc[4][5]); one
//         LDS-staged epilogue reusing nbB, copy-out as full 512B coalesced
//         rows (was per-atile 2B column scatter at stride 4KB).
#define ZNX_PAD 264  // row STRIDE in bf16: 256 data + 8 pad
__global__ __launch_bounds__(256, 2) void znx_k(const float* __restrict__ x,
        const float* __restrict__ t, const float* __restrict__ rdenom,
        const float* __restrict__ nb, __hip_bfloat16* __restrict__ Abuf) {
    int bc = blockIdx.x;
    int b = bc >> 3, c = bc & 7;
    int tid = threadIdx.x;
    int wave = tid >> 6, lane = tid & 63;
    __shared__ float xs[F_], ts[F_];
    __shared__ __hip_bfloat16 nbB[80 * ZNX_PAD];  // 42240 B

    xs[tid] = x[(size_t)bc * F_ + tid];
    ts[tid] = t[(size_t)bc * F_ + tid];
    {
        int r = tid >> 2, cs0 = (tid & 3) * 64;
        const float* src = nb + (((size_t)(b * N_ + r)) * C_ + c) * F_ + cs0;
        __hip_bfloat16* dst = nbB + r * ZNX_PAD + cs0;
        #pragma unroll
        for (int j = 0; j < 64; j += 4) {
            float4 v = *(const float4*)(src + j);
            ushort4 u = { bfbits(v.x), bfbits(v.y), bfbits(v.z), bfbits(v.w) };
            *(ushort4*)(&dst[j]) = u;          // 8B-aligned packed write
        }
    }
    if (tid < 64) {
        float4 v = *(const float4*)(x + (size_t)bc * F_ + tid * 4);
        ushort4 u = { bfbits(v.x), bfbits(v.y), bfbits(v.z), bfbits(v.w) };
        *(ushort4*)(&nbB[64 * ZNX_PAD + tid * 4]) = u;
    }
    {
        __hip_bfloat16 z = __float2bfloat16(0.f);
        #pragma unroll
        for (int j = 0; j < 16; ++j) {
            int o = 65 * ZNX_PAD + tid * 16 + j;
            if (o < 80 * ZNX_PAD) nbB[o] = z;
        }
    }
    __syncthreads();

    const int aq = lane & 15;
    const int dq = lane >> 4;
    f32x4 acc[4][5] = {};   // [atile][mt] -- all compile-time indexed
    #pragma unroll
    for (int atile = 0; atile < 4; ++atile) {
        int a = wave * 64 + atile * 16 + aq;
        float xa = xs[a], ta = ts[a];
        const float* drow = rdenom + ((size_t)b * F_ + a) * F_;
        #pragma unroll
        for (int kc = 0; kc < 8; ++kc) {
            int d0 = kc * 32 + dq * 8;
            float4 xv0 = *(const float4*)(xs + d0);
            float4 xv1 = *(const float4*)(xs + d0 + 4);
            float4 tv0 = *(const float4*)(ts + d0);
            float4 tv1 = *(const float4*)(ts + d0 + 4);
            float4 dn0 = *(const float4*)(drow + d0);
            float4 dn1 = *(const float4*)(drow + d0 + 4);
            float xv[8] = {xv0.x, xv0.y, xv0.z, xv0.w, xv1.x, xv1.y, xv1.z, xv1.w};
            float tv[8] = {tv0.x, tv0.y, tv0.z, tv0.w, tv1.x, tv1.y, tv1.z, tv1.w};
            float dn[8] = {dn0.x, dn0.y, dn0.z, dn0.w, dn1.x, dn1.y, dn1.z, dn1.w};
            union { bf16x8 v; __hip_bfloat16 h[8]; } bu;
            #pragma unroll
            for (int j = 0; j < 8; ++j) {
                float g = sgnroot_dev(xa * tv[j] + xv[j] * ta);
                bu.h[j] = __float2bfloat16(g * dn[j]);   // dn = 1/denom
            }
            #pragma unroll
            for (int mt = 0; mt < 5; ++mt) {
                bf16x8 af = *(const bf16x8*)(nbB + (mt * 16 + aq) * ZNX_PAD
                                             + kc * 32 + dq * 8);
                acc[atile][mt] = __builtin_amdgcn_mfma_f32_16x16x32_bf16(
                    af, bu.v, acc[atile][mt], 0, 0, 0);
            }
        }
    }

    // ---- epilogue: stage [65 rows x 256 cols] bf16 tile into nbB, then
    //      copy out as full coalesced rows (one 512B row per wave per iter).
    __syncthreads();   // all waves done READING nbB before overwrite
    #pragma unroll
    for (int atile = 0; atile < 4; ++atile) {
        int a = wave * 64 + atile * 16 + aq;
        #pragma unroll
        for (int mt = 0; mt < 4; ++mt) {
            #pragma unroll
            for (int i = 0; i < 4; ++i) {
                int n = mt * 16 + dq * 4 + i;
                nbB[n * ZNX_PAD + a] = __float2bfloat16(acc[atile][mt][i]);
            }
        }
        if (dq == 0)
            nbB[64 * ZNX_PAD + a] = __float2bfloat16(acc[atile][4][0]);
    }
    __syncthreads();
    // 65 rows x 512B = 4160 8B-chunks; chunk q -> row q>>6, bf16 off (q&63)*4
    for (int it = 0; it < 17; ++it) {
        int q = it * 256 + tid;
        if (q < 4160) {
            int row = q >> 6;
            int off = (q & 63) * 4;
            ushort4 u = *(const ushort4*)(&nbB[row * ZNX_PAD + off]);
            int grow = (row < 64) ? (64 + b * N_ + row) : b;
            *(ushort4*)(&Abuf[(size_t)grow * K_ + c * F_ + off]) = u;
        }
    }
}

// ---------------------------------------------------------------------------
// C[M_TOT, 2048] = A[M_TOT, 2048] @ B[2048, 2048]^T, bf16 in, fp32 out.
// SWIZZLED row-major LDS (staging coalesced + reads conflict-free,
// SQ_LDS_BANK_CONFLICT == 0 verified). 3-deep counted-vmcnt pipeline
// (T3+T4, verified R2: 95->64.7us). R3: + T5 s_setprio around the MFMA
// cluster (schedule has wave role-diversity -> setprio has something to
// arbitrate, per m218b/m224).
__global__ __launch_bounds__(256) void gemm_bf16_k(
        const __hip_bfloat16* __restrict__ A,
        const __hip_bfloat16* __restrict__ Bm,
        float* __restrict__ Cm) {
    __shared__ char lds[49152] __attribute__((aligned(16)));  // 3 x (8K A + 8K B)
    const int t = threadIdx.x;
    const int wave = t >> 6;
    const int lane = t & 63;
    const int col0 = blockIdx.x * 128;
    const int row0 = blockIdx.y * 128;
    const int wrow0 = (wave & 1) * 64;
    const int wcol0 = (wave >> 1) * 64;
    const int aq = lane & 15;
    const int dq = lane >> 4;

    const int rA0 = t >> 2;                               // row 0..63 (issue 0)
    const int kcs = ((t & 3) - ((t >> 3) & 3)) & 3;       // swizzled k-chunk
    const int kc = kcs * 8;                               // element offset
    const int grA0 = min(row0 + rA0, M_TOT - 1);
    const int grA1 = min(row0 + rA0 + 64, M_TOT - 1);
    const int gcB0 = col0 + rA0;
    const int gcB1 = col0 + rA0 + 64;
    const size_t aoff0 = (size_t)grA0 * K_ + kc;
    const size_t aoff1 = (size_t)grA1 * K_ + kc;
    const size_t boff0 = (size_t)gcB0 * K_ + kc;
    const size_t boff1 = (size_t)gcB1 * K_ + kc;
    const int swz = ((dq + (aq >> 1)) & 3) * 16;          // read-side position
    const int ldsw = wave * 1024;

    f32x4 acc[4][4] = {};

#define STAGE(BI, TK) do {                                                     \
    const int k0_ = (TK) * 32;                                                 \
    char* la_ = lds + (BI) * 16384 + ldsw;                                     \
    char* lb_ = la_ + 8192;                                                    \
    __builtin_amdgcn_global_load_lds(                                          \
        (const __attribute__((address_space(1))) void*)(A + aoff0 + k0_),      \
        (__attribute__((address_space(3))) void*)la_, 16, 0, 0);               \
    __builtin_amdgcn_global_load_lds(                                          \
        (const __attribute__((address_space(1))) void*)(A + aoff1 + k0_),      \
        (__attribute__((address_space(3))) void*)(la_ + 4096), 16, 0, 0);      \
    __builtin_amdgcn_global_load_lds(                                          \
        (const __attribute__((address_space(1))) void*)(Bm + boff0 + k0_),     \
        (__attribute__((address_space(3))) void*)lb_, 16, 0, 0);               \
    __builtin_amdgcn_global_load_lds(                                          \
        (const __attribute__((address_space(1))) void*)(Bm + boff1 + k0_),     \
        (__attribute__((address_space(3))) void*)(lb_ + 4096), 16, 0, 0);      \
} while (0)

#define COMPUTE(BI) do {                                                       \
    const char* la_ = lds + (BI) * 16384;                                      \
    const char* lb_ = la_ + 8192;                                              \
    bf16x8 af_[4], bf_[4];                                                     \
    _Pragma("unroll")                                                          \
    for (int rb = 0; rb < 4; ++rb)                                             \
        af_[rb] = *(const bf16x8*)(la_ + (wrow0 + rb * 16 + aq) * 64 + swz);   \
    _Pragma("unroll")                                                          \
    for (int cb = 0; cb < 4; ++cb)                                             \
        bf_[cb] = *(const bf16x8*)(lb_ + (wcol0 + cb * 16 + aq) * 64 + swz);   \
    __builtin_amdgcn_s_setprio(1);                                             \
    _Pragma("unroll")                                                          \
    for (int rb = 0; rb < 4; ++rb)                                             \
        _Pragma("unroll")                                                      \
        for (int cb = 0; cb < 4; ++cb)                                         \
            acc[rb][cb] = __builtin_amdgcn_mfma_f32_16x16x32_bf16(             \
                af_[rb], bf_[cb], acc[rb][cb], 0, 0, 0);                       \
    __builtin_amdgcn_s_setprio(0);                                             \
} while (0)

#define WAIT_PIPE(N) do {                                                      \
    asm volatile("s_waitcnt vmcnt(" #N ")" ::: "memory");                      \
    __builtin_amdgcn_sched_barrier(0);                                         \
    __builtin_amdgcn_s_barrier();                                              \
    __builtin_amdgcn_sched_barrier(0);                                         \
} while (0)

    // Prologue: fill the 3-deep pipeline (12 loads in flight per wave).
    STAGE(0, 0);
    STAGE(1, 1);
    STAGE(2, 2);

    // Steady state: tiles 0..59 (20 triples). At tile t: wait for tile t
    // (my 4 oldest of 12 in flight -> vmcnt(8)), barrier, compute, barrier,
    // refill the freed buffer with tile t+3.
    for (int t3 = 0; t3 < 60; t3 += 3) {
        WAIT_PIPE(8);
        COMPUTE(0);
        __builtin_amdgcn_s_barrier();
        STAGE(0, t3 + 3);

        WAIT_PIPE(8);
        COMPUTE(1);
        __builtin_amdgcn_s_barrier();
        STAGE(1, t3 + 4);

        WAIT_PIPE(8);
        COMPUTE(2);
        __builtin_amdgcn_s_barrier();
        STAGE(2, t3 + 5);
    }
    // tile 60 (buf0), then stage tile 63 into buf0.
    WAIT_PIPE(8);
    COMPUTE(0);
    __builtin_amdgcn_s_barrier();
    STAGE(0, 63);
    // tile 61: tiles 61,62,63 in flight -> wait tile 61 (vmcnt(8)).
    WAIT_PIPE(8);
    COMPUTE(1);
    // tile 62: tiles 62,63 in flight -> wait tile 62 (vmcnt(4)).
    WAIT_PIPE(4);
    COMPUTE(2);
    // tile 63: drain.
    WAIT_PIPE(0);
    COMPUTE(0);

#undef STAGE
#undef COMPUTE
#undef WAIT_PIPE

    #pragma unroll
    for (int rb = 0; rb < 4; ++rb) {
        int rowbase = row0 + wrow0 + rb * 16 + (lane >> 4) * 4;
        #pragma unroll
        for (int cb = 0; cb < 4; ++cb) {
            int col = col0 + wcol0 + cb * 16 + (lane & 15);
            #pragma unroll
            for (int i = 0; i < 4; ++i) {
                int row = rowbase + i;
                if (row < M_TOT)
                    Cm[(size_t)row * NO_ + col] = acc[rb][cb][i];
            }
        }
    }
}

// ---------------------------------------------------------------------------
extern "C" void kernel_launch(void* const* d_in, const int* in_sizes, int n_in,
                              void* d_out, int out_size, void* d_ws, size_t ws_size,
                              hipStream_t stream) {
    const float* x  = (const float*)d_in[0];
    const float* nb = (const float*)d_in[1];
    const float* W1 = (const float*)d_in[2];
    const float* W2 = (const float*)d_in[3];
    const float* Wc = (const float*)d_in[4];
    float* out = (float*)d_out;
    float* ws = (float*)d_ws;

    float* s1    = ws;            // 64 f
    float* s2    = ws + 64;       // 4096 f
    float* t     = ws + 4160;     // 131072 f
    float* rden  = ws + 135232;   // 4194304 f (B*F*F), stores 1/denom
    __hip_bfloat16* Abuf = (__hip_bfloat16*)(ws + 4329536);   // 4160*2048 bf16
    __hip_bfloat16* Bbuf = Abuf + (size_t)M_TOT * K_;         // 2048*2048 bf16

    hipLaunchKernelGGL(sums_wc_k, dim3(B_ * N_ + B_ + (K_ * NO_) / 1024),
                       dim3(256), 0, stream, x, nb, W1, W2, Wc, s1, s2, Bbuf);
    hipLaunchKernelGGL(t_k, dim3(B_ * C_), dim3(1024), 0, stream, nb, s1, s2, t);
    hipLaunchKernelGGL(denom_k, dim3(B_ * F_), dim3(256), 0, stream, x, t, rden);
    hipLaunchKernelGGL(znx_k, dim3(B_ * C_), dim3(256), 0, stream,
                       x, t, rden, nb, Abuf);
    hipLaunchKernelGGL(gemm_bf16_k, dim3(16, 33), dim3(256), 0, stream,
                       Abuf, Bbuf, out);
}

// Round 4
// 201.063 us; speedup vs baseline: 1.0409x; 1.0409x over previous
//
#include <hip/hip_runtime.h>
#include <hip/hip_bf16.h>
#include <math.h>

#define B_ 64
#define N_ 64
#define C_ 8
#define F_ 256
#define K_ 2048    // C_*F_
#define NO_ 2048   // OC_*OF_
#define M_TOT 4160 // 64 (zx rows) + 4096 (zn rows)

typedef __attribute__((ext_vector_type(8))) short bf16x8;  // 8 bf16 = 4 VGPRs
typedef __attribute__((ext_vector_type(4))) float f32x4;

__device__ __forceinline__ unsigned short bfbits(float f) {
    union { __hip_bfloat16 h; unsigned short u; } cv;
    cv.h = __float2bfloat16(f);
    return cv.u;
}

// ---------------------------------------------------------------------------
// Fused: s1[b], s2[b,n] reductions + Wc fp32->bf16 conversion.
// blk < 4096: s2;  4096..4159: s1;  >=4160: wc convert.
__global__ __launch_bounds__(256) void sums_wc_k(const float* __restrict__ x,
        const float* __restrict__ nb, const float* __restrict__ W1,
        const float* __restrict__ W2, const float* __restrict__ Wc,
        float* __restrict__ s1, float* __restrict__ s2,
        __hip_bfloat16* __restrict__ Bbuf) {
    int blk = blockIdx.x;
    int f = threadIdx.x;
    if (blk >= B_ * N_ + B_) {
        int i = (blk - (B_ * N_ + B_)) * 1024 + f * 4;
        float4 v = *(const float4*)(Wc + i);
        ushort4 u = { bfbits(v.x), bfbits(v.y), bfbits(v.z), bfbits(v.w) };
        *(ushort4*)(&Bbuf[i]) = u;            // one 8B store (was 4x 2B)
        return;
    }
    float val;
    if (blk < B_ * N_) {
        const float* base = nb + (size_t)blk * (C_ * F_);
        float wsum = 0.f;
        #pragma unroll
        for (int k = 0; k < C_; ++k) wsum += W2[k * F_ + f];
        float cs = 0.f;
        #pragma unroll
        for (int c = 0; c < C_; ++c) cs += base[c * F_ + f];
        val = cs * wsum;
    } else {
        int b = blk - B_ * N_;
        const float* base = x + (size_t)b * (C_ * F_);
        float wsum = 0.f;
        #pragma unroll
        for (int k = 0; k < C_; ++k) wsum += W1[k * F_ + f];
        float cs = 0.f;
        #pragma unroll
        for (int c = 0; c < C_; ++c) cs += base[c * F_ + f];
        val = cs * wsum;
    }
    #pragma unroll
    for (int off = 32; off > 0; off >>= 1) val += __shfl_down(val, off, 64);
    __shared__ float wred[4];
    int w = f >> 6;
    if ((f & 63) == 0) wred[w] = val;
    __syncthreads();
    if (f == 0) {
        float s = wred[0] + wred[1] + wred[2] + wred[3];
        if (blk < B_ * N_) s2[blk] = s;
        else s1[blk - B_ * N_] = s;
    }
}

// ---------------------------------------------------------------------------
// t[b,c,d] = s1[b] * sum_n nb[b,n,c,d] * s2[b,n]
__global__ __launch_bounds__(1024) void t_k(const float* __restrict__ nb,
        const float* __restrict__ s1, const float* __restrict__ s2,
        float* __restrict__ t) {
    int blk = blockIdx.x;  // b*C_ + c
    int b = blk / C_, c = blk % C_;
    int tid = threadIdx.x;
    int q = tid >> 8, d = tid & 255;
    const float* p = nb + ((size_t)(b * N_) * C_ + c) * F_ + d;
    const float* s2p = s2 + b * N_;
    float acc = 0.f;
    #pragma unroll
    for (int j = 0; j < 16; ++j) {
        int n = q * 16 + j;
        acc += p[(size_t)n * C_ * F_] * s2p[n];
    }
    __shared__ float part[4][F_];
    part[q][d] = acc;
    __syncthreads();
    if (tid < 256) {
        float s = part[0][d] + part[1][d] + part[2][d] + part[3][d];
        t[(size_t)blk * F_ + d] = s * s1[b];
    }
}

// ---------------------------------------------------------------------------
// rdenom[b,a,d] = 1 / (1e-7 + sum_c |sgnroot(x_a t_d + x_d t_a)|)
__global__ __launch_bounds__(256) void denom_k(const float* __restrict__ x,
        const float* __restrict__ t, float* __restrict__ rdenom) {
    int blk = blockIdx.x;  // b*F_ + a
    int b = blk >> 8, a = blk & 255;
    int d = threadIdx.x;
    float acc = 1e-7f;
    #pragma unroll
    for (int c = 0; c < C_; ++c) {
        size_t o = ((size_t)b * C_ + c) * F_;
        float xa = x[o + a], ta = t[o + a];
        float xd = x[o + d], td = t[o + d];
        float v = xa * td + xd * ta;
        float r = __builtin_amdgcn_sqrtf(fmaxf(fabsf(v), 1e-8f));
        acc += (v != 0.f) ? r : 0.f;
    }
    rdenom[(size_t)blk * F_ + d] = __builtin_amdgcn_rcpf(acc);
}

__device__ __forceinline__ float sgnroot_dev(float v) {
    float r = __builtin_amdgcn_sqrtf(fmaxf(fabsf(v), 1e-8f));
    return (v > 0.f) ? r : ((v < 0.f) ? -r : 0.f);
}

// ---------------------------------------------------------------------------
// Fused zx+zn via MFMA. One block per (b,c).
// R3 (verified, kept): packed 8B LDS staging writes; all-atile register
// accumulators; LDS-staged epilogue with coalesced 512B row copy-out.
#define ZNX_PAD 264  // row STRIDE in bf16: 256 data + 8 pad
__global__ __launch_bounds__(256, 2) void znx_k(const float* __restrict__ x,
        const float* __restrict__ t, const float* __restrict__ rdenom,
        const float* __restrict__ nb, __hip_bfloat16* __restrict__ Abuf) {
    int bc = blockIdx.x;
    int b = bc >> 3, c = bc & 7;
    int tid = threadIdx.x;
    int wave = tid >> 6, lane = tid & 63;
    __shared__ float xs[F_], ts[F_];
    __shared__ __hip_bfloat16 nbB[80 * ZNX_PAD];  // 42240 B

    xs[tid] = x[(size_t)bc * F_ + tid];
    ts[tid] = t[(size_t)bc * F_ + tid];
    {
        int r = tid >> 2, cs0 = (tid & 3) * 64;
        const float* src = nb + (((size_t)(b * N_ + r)) * C_ + c) * F_ + cs0;
        __hip_bfloat16* dst = nbB + r * ZNX_PAD + cs0;
        #pragma unroll
        for (int j = 0; j < 64; j += 4) {
            float4 v = *(const float4*)(src + j);
            ushort4 u = { bfbits(v.x), bfbits(v.y), bfbits(v.z), bfbits(v.w) };
            *(ushort4*)(&dst[j]) = u;          // 8B-aligned packed write
        }
    }
    if (tid < 64) {
        float4 v = *(const float4*)(x + (size_t)bc * F_ + tid * 4);
        ushort4 u = { bfbits(v.x), bfbits(v.y), bfbits(v.z), bfbits(v.w) };
        *(ushort4*)(&nbB[64 * ZNX_PAD + tid * 4]) = u;
    }
    {
        __hip_bfloat16 z = __float2bfloat16(0.f);
        #pragma unroll
        for (int j = 0; j < 16; ++j) {
            int o = 65 * ZNX_PAD + tid * 16 + j;
            if (o < 80 * ZNX_PAD) nbB[o] = z;
        }
    }
    __syncthreads();

    const int aq = lane & 15;
    const int dq = lane >> 4;
    f32x4 acc[4][5] = {};   // [atile][mt] -- all compile-time indexed
    #pragma unroll
    for (int atile = 0; atile < 4; ++atile) {
        int a = wave * 64 + atile * 16 + aq;
        float xa = xs[a], ta = ts[a];
        const float* drow = rdenom + ((size_t)b * F_ + a) * F_;
        #pragma unroll
        for (int kc = 0; kc < 8; ++kc) {
            int d0 = kc * 32 + dq * 8;
            float4 xv0 = *(const float4*)(xs + d0);
            float4 xv1 = *(const float4*)(xs + d0 + 4);
            float4 tv0 = *(const float4*)(ts + d0);
            float4 tv1 = *(const float4*)(ts + d0 + 4);
            float4 dn0 = *(const float4*)(drow + d0);
            float4 dn1 = *(const float4*)(drow + d0 + 4);
            float xv[8] = {xv0.x, xv0.y, xv0.z, xv0.w, xv1.x, xv1.y, xv1.z, xv1.w};
            float tv[8] = {tv0.x, tv0.y, tv0.z, tv0.w, tv1.x, tv1.y, tv1.z, tv1.w};
            float dn[8] = {dn0.x, dn0.y, dn0.z, dn0.w, dn1.x, dn1.y, dn1.z, dn1.w};
            union { bf16x8 v; __hip_bfloat16 h[8]; } bu;
            #pragma unroll
            for (int j = 0; j < 8; ++j) {
                float g = sgnroot_dev(xa * tv[j] + xv[j] * ta);
                bu.h[j] = __float2bfloat16(g * dn[j]);   // dn = 1/denom
            }
            #pragma unroll
            for (int mt = 0; mt < 5; ++mt) {
                bf16x8 af = *(const bf16x8*)(nbB + (mt * 16 + aq) * ZNX_PAD
                                             + kc * 32 + dq * 8);
                acc[atile][mt] = __builtin_amdgcn_mfma_f32_16x16x32_bf16(
                    af, bu.v, acc[atile][mt], 0, 0, 0);
            }
        }
    }

    // ---- epilogue: stage [65 rows x 256 cols] bf16 tile into nbB, then
    //      copy out as full coalesced rows (one 512B row per wave per iter).
    __syncthreads();   // all waves done READING nbB before overwrite
    #pragma unroll
    for (int atile = 0; atile < 4; ++atile) {
        int a = wave * 64 + atile * 16 + aq;
        #pragma unroll
        for (int mt = 0; mt < 4; ++mt) {
            #pragma unroll
            for (int i = 0; i < 4; ++i) {
                int n = mt * 16 + dq * 4 + i;
                nbB[n * ZNX_PAD + a] = __float2bfloat16(acc[atile][mt][i]);
            }
        }
        if (dq == 0)
            nbB[64 * ZNX_PAD + a] = __float2bfloat16(acc[atile][4][0]);
    }
    __syncthreads();
    // 65 rows x 512B = 4160 8B-chunks; chunk q -> row q>>6, bf16 off (q&63)*4
    for (int it = 0; it < 17; ++it) {
        int q = it * 256 + tid;
        if (q < 4160) {
            int row = q >> 6;
            int off = (q & 63) * 4;
            ushort4 u = *(const ushort4*)(&nbB[row * ZNX_PAD + off]);
            int grow = (row < 64) ? (64 + b * N_ + row) : b;
            *(ushort4*)(&Abuf[(size_t)grow * K_ + c * F_ + off]) = u;
        }
    }
}

// ---------------------------------------------------------------------------
// C[M_TOT, 2048] = A[M_TOT, 2048] @ B[2048, 2048]^T, bf16 in, fp32 out.
// SWIZZLED row-major LDS (staging coalesced + reads conflict-free,
// SQ_LDS_BANK_CONFLICT == 0 verified). Counted-vmcnt pipeline (T3+T4,
// verified R2: 95->64.7us at depth 3).
// R4: (a) setprio REVERTED (R3 A/B: lockstep schedule -> T5 hurts, -17%);
//     (b) pipeline deepened 3->4 buffers (64 KiB LDS; occupancy is
//         grid-limited to 2 blocks/CU so extra LDS is free; steady-state
//         vmcnt(12) = 12 loads in flight, 3 phases of latency cover).
__global__ __launch_bounds__(256) void gemm_bf16_k(
        const __hip_bfloat16* __restrict__ A,
        const __hip_bfloat16* __restrict__ Bm,
        float* __restrict__ Cm) {
    __shared__ char lds[65536] __attribute__((aligned(16)));  // 4 x (8K A + 8K B)
    const int t = threadIdx.x;
    const int wave = t >> 6;
    const int lane = t & 63;
    const int col0 = blockIdx.x * 128;
    const int row0 = blockIdx.y * 128;
    const int wrow0 = (wave & 1) * 64;
    const int wcol0 = (wave >> 1) * 64;
    const int aq = lane & 15;
    const int dq = lane >> 4;

    const int rA0 = t >> 2;                               // row 0..63 (issue 0)
    const int kcs = ((t & 3) - ((t >> 3) & 3)) & 3;       // swizzled k-chunk
    const int kc = kcs * 8;                               // element offset
    const int grA0 = min(row0 + rA0, M_TOT - 1);
    const int grA1 = min(row0 + rA0 + 64, M_TOT - 1);
    const int gcB0 = col0 + rA0;
    const int gcB1 = col0 + rA0 + 64;
    const size_t aoff0 = (size_t)grA0 * K_ + kc;
    const size_t aoff1 = (size_t)grA1 * K_ + kc;
    const size_t boff0 = (size_t)gcB0 * K_ + kc;
    const size_t boff1 = (size_t)gcB1 * K_ + kc;
    const int swz = ((dq + (aq >> 1)) & 3) * 16;          // read-side position
    const int ldsw = wave * 1024;

    f32x4 acc[4][4] = {};

#define STAGE(BI, TK) do {                                                     \
    const int k0_ = (TK) * 32;                                                 \
    char* la_ = lds + (BI) * 16384 + ldsw;                                     \
    char* lb_ = la_ + 8192;                                                    \
    __builtin_amdgcn_global_load_lds(                                          \
        (const __attribute__((address_space(1))) void*)(A + aoff0 + k0_),      \
        (__attribute__((address_space(3))) void*)la_, 16, 0, 0);               \
    __builtin_amdgcn_global_load_lds(                                          \
        (const __attribute__((address_space(1))) void*)(A + aoff1 + k0_),      \
        (__attribute__((address_space(3))) void*)(la_ + 4096), 16, 0, 0);      \
    __builtin_amdgcn_global_load_lds(                                          \
        (const __attribute__((address_space(1))) void*)(Bm + boff0 + k0_),     \
        (__attribute__((address_space(3))) void*)lb_, 16, 0, 0);               \
    __builtin_amdgcn_global_load_lds(                                          \
        (const __attribute__((address_space(1))) void*)(Bm + boff1 + k0_),     \
        (__attribute__((address_space(3))) void*)(lb_ + 4096), 16, 0, 0);      \
} while (0)

#define COMPUTE(BI) do {                                                       \
    const char* la_ = lds + (BI) * 16384;                                      \
    const char* lb_ = la_ + 8192;                                              \
    bf16x8 af_[4], bf_[4];                                                     \
    _Pragma("unroll")                                                          \
    for (int rb = 0; rb < 4; ++rb)                                             \
        af_[rb] = *(const bf16x8*)(la_ + (wrow0 + rb * 16 + aq) * 64 + swz);   \
    _Pragma("unroll")                                                          \
    for (int cb = 0; cb < 4; ++cb)                                             \
        bf_[cb] = *(const bf16x8*)(lb_ + (wcol0 + cb * 16 + aq) * 64 + swz);   \
    _Pragma("unroll")                                                          \
    for (int rb = 0; rb < 4; ++rb)                                             \
        _Pragma("unroll")                                                      \
        for (int cb = 0; cb < 4; ++cb)                                         \
            acc[rb][cb] = __builtin_amdgcn_mfma_f32_16x16x32_bf16(             \
                af_[rb], bf_[cb], acc[rb][cb], 0, 0, 0);                       \
} while (0)

#define WAIT_PIPE(N) do {                                                      \
    asm volatile("s_waitcnt vmcnt(" #N ")" ::: "memory");                      \
    __builtin_amdgcn_sched_barrier(0);                                         \
    __builtin_amdgcn_s_barrier();                                              \
    __builtin_amdgcn_sched_barrier(0);                                         \
} while (0)

    // Prologue: fill the 4-deep pipeline (16 loads in flight per wave).
    STAGE(0, 0);
    STAGE(1, 1);
    STAGE(2, 2);
    STAGE(3, 3);

    // Steady state: tiles 0..59 (15 quads). At tile t: wait for tile t
    // (my 4 oldest of 16 in flight -> vmcnt(12)), barrier, compute, barrier,
    // refill the freed buffer with tile t+4.
    for (int t4 = 0; t4 < 60; t4 += 4) {
        WAIT_PIPE(12);
        COMPUTE(0);
        __builtin_amdgcn_s_barrier();
        STAGE(0, t4 + 4);

        WAIT_PIPE(12);
        COMPUTE(1);
        __builtin_amdgcn_s_barrier();
        STAGE(1, t4 + 5);

        WAIT_PIPE(12);
        COMPUTE(2);
        __builtin_amdgcn_s_barrier();
        STAGE(2, t4 + 6);

        WAIT_PIPE(12);
        COMPUTE(3);
        __builtin_amdgcn_s_barrier();
        STAGE(3, t4 + 7);
    }
    // Epilogue: tiles 60..63 in flight (16 loads), no more staging.
    WAIT_PIPE(12);
    COMPUTE(0);
    WAIT_PIPE(8);
    COMPUTE(1);
    WAIT_PIPE(4);
    COMPUTE(2);
    WAIT_PIPE(0);
    COMPUTE(3);

#undef STAGE
#undef COMPUTE
#undef WAIT_PIPE

    #pragma unroll
    for (int rb = 0; rb < 4; ++rb) {
        int rowbase = row0 + wrow0 + rb * 16 + (lane >> 4) * 4;
        #pragma unroll
        for (int cb = 0; cb < 4; ++cb) {
            int col = col0 + wcol0 + cb * 16 + (lane & 15);
            #pragma unroll
            for (int i = 0; i < 4; ++i) {
                int row = rowbase + i;
                if (row < M_TOT)
                    Cm[(size_t)row * NO_ + col] = acc[rb][cb][i];
            }
        }
    }
}

// ---------------------------------------------------------------------------
extern "C" void kernel_launch(void* const* d_in, const int* in_sizes, int n_in,
                              void* d_out, int out_size, void* d_ws, size_t ws_size,
                              hipStream_t stream) {
    const float* x  = (const float*)d_in[0];
    const float* nb = (const float*)d_in[1];
    const float* W1 = (const float*)d_in[2];
    const float* W2 = (const float*)d_in[3];
    const float* Wc = (const float*)d_in[4];
    float* out = (float*)d_out;
    float* ws = (float*)d_ws;

    float* s1    = ws;            // 64 f
    float* s2    = ws + 64;       // 4096 f
    float* t     = ws + 4160;     // 131072 f
    float* rden  = ws + 135232;   // 4194304 f (B*F*F), stores 1/denom
    __hip_bfloat16* Abuf = (__hip_bfloat16*)(ws + 4329536);   // 4160*2048 bf16
    __hip_bfloat16* Bbuf = Abuf + (size_t)M_TOT * K_;         // 2048*2048 bf16

    hipLaunchKernelGGL(sums_wc_k, dim3(B_ * N_ + B_ + (K_ * NO_) / 1024),
                       dim3(256), 0, stream, x, nb, W1, W2, Wc, s1, s2, Bbuf);
    hipLaunchKernelGGL(t_k, dim3(B_ * C_), dim3(1024), 0, stream, nb, s1, s2, t);
    hipLaunchKernelGGL(denom_k, dim3(B_ * F_), dim3(256), 0, stream, x, t, rden);
    hipLaunchKernelGGL(znx_k, dim3(B_ * C_), dim3(256), 0, stream,
                       x, t, rden, nb, Abuf);
    hipLaunchKernelGGL(gemm_bf16_k, dim3(16, 33), dim3(256), 0, stream,
                       Abuf, Bbuf, out);
}